// Round 3
// baseline (185.167 us; speedup 1.0000x reference)
//
#include <hip/hip_runtime.h>
#include <hip/hip_bf16.h>

// RoI bilinear pooling, locality-scheduled.
// img : (1, H=200, W=200, C=256) fp32 NHWC -> channel vectors contiguous (1 KiB)
// rois: (1, N=2000, 4) fp32 (integer-valued x,y,w,h)
// out : (1, N, ps, ps, C) fp32
//
// R1 post-mortem: tap demand is 392 MB vs 41 MB image; reuse is cross-RoI only
// (a big RoI's 196 tap refs hit ~196 distinct pixels). Random RoI order made the
// concurrent working set span the whole image -> FETCH 159 MB. Fix: counting-sort
// the 14000 (roi,py) output rows by their image row gy0 so concurrently-resident
// waves touch one narrow horizontal band and the y-sweep is monotone -> each
// image byte fetched ~once.

typedef float f32x4 __attribute__((ext_vector_type(4)));

#define IMG_H 200
#define IMG_W 200
#define NBINS 256   // gy0 in [0,199]

__device__ __forceinline__ int row_gy0(const float4 r, int py, int ps) {
    const int y = (int)r.y;
    const int h = (int)r.w;
    const float sy    = (float)h / (float)ps;
    const float src_y = (float)py * sy;
    const int   y0    = (int)floorf(src_y);
    return min(max(y + min(max(y0, 0), h - 1), 0), IMG_H - 1);
}

// --- pass 1: zero bins, then histogram of gy0 over all rows ---
__global__ void zero_bins_kernel(int* __restrict__ bins) {
    bins[threadIdx.x] = 0;   // 1 block x NBINS threads
}

__global__ void hist_kernel(const float* __restrict__ rois, int* __restrict__ bins,
                            int n_rows, int ps) {
    const int row = blockIdx.x * blockDim.x + threadIdx.x;
    if (row >= n_rows) return;
    const int roi = row / ps;
    const int py  = row - roi * ps;
    const float4 r = reinterpret_cast<const float4*>(rois)[roi];
    atomicAdd(&bins[row_gy0(r, py, ps)], 1);
}

// --- pass 2: exclusive prefix sum over NBINS (single thread; 256 iters) ---
__global__ void scan_kernel(const int* __restrict__ bins, int* __restrict__ offs) {
    if (threadIdx.x == 0) {
        int acc = 0;
        for (int i = 0; i < NBINS; ++i) { offs[i] = acc; acc += bins[i]; }
    }
}

// --- pass 3: scatter row ids into sorted order ---
__global__ void scatter_kernel(const float* __restrict__ rois, int* __restrict__ offs,
                               int* __restrict__ rowmap, int n_rows, int ps) {
    const int row = blockIdx.x * blockDim.x + threadIdx.x;
    if (row >= n_rows) return;
    const int roi = row / ps;
    const int py  = row - roi * ps;
    const float4 r = reinterpret_cast<const float4*>(rois)[roi];
    const int pos = atomicAdd(&offs[row_gy0(r, py, ps)], 1);
    rowmap[pos] = row;
}

// --- main kernel: one wave per output row, rows visited in sorted-y order ---
__global__ __launch_bounds__(256) void RoIPool_53575422050620_kernel(
    const float* __restrict__ feat,     // H*W*C
    const float* __restrict__ rois,     // N*4
    const int*   __restrict__ rowmap,   // sorted row ids
    float*       __restrict__ out,      // N*ps*ps*C
    int n_rows, int H, int W, int C, int ps)
{
    const int slot = blockIdx.x * 4 + (threadIdx.x >> 6);
    if (slot >= n_rows) return;
    const int row  = rowmap[slot];
    const int lane = threadIdx.x & 63;

    const int roi = row / ps;
    const int py  = row - roi * ps;

    const float4 r = reinterpret_cast<const float4*>(rois)[roi];
    const int x = (int)r.x;   // astype(int32) == trunc; values >= 0
    const int y = (int)r.y;
    const int w = (int)r.z;
    const int h = (int)r.w;

    // y-side math, identical fp32 expression to reference
    const float sy    = (float)h / (float)ps;
    const float sx    = (float)w / (float)ps;
    const float src_y = (float)py * sy;
    const int   y0    = (int)floorf(src_y);
    const float wy    = src_y - (float)y0;
    const float omwy  = 1.0f - wy;

    const int gy0 = min(max(y + min(max(y0,     0), h - 1), 0), H - 1);
    const int gy1 = min(max(y + min(max(y0 + 1, 0), h - 1), 0), H - 1);

    const int C4 = C >> 2;   // == 64: one float4 per lane covers the channel row
    const f32x4* __restrict__ f4 = reinterpret_cast<const f32x4*>(feat);
    f32x4* __restrict__ o4 = reinterpret_cast<f32x4*>(out);

    const size_t r0 = (size_t)(gy0 * W) * C4 + lane;
    const size_t r1 = (size_t)(gy1 * W) * C4 + lane;
    const size_t ob = (size_t)row * ps * C4 + lane;

    auto body = [&](int px) {
        const float src_x = (float)px * sx;
        const int   x0    = (int)floorf(src_x);
        const float wx    = src_x - (float)x0;
        const float omwx  = 1.0f - wx;

        const int gx0 = min(max(x + min(max(x0,     0), w - 1), 0), W - 1);
        const int gx1 = min(max(x + min(max(x0 + 1, 0), w - 1), 0), W - 1);

        const f32x4 v00 = f4[r0 + (size_t)gx0 * C4];
        const f32x4 v01 = f4[r0 + (size_t)gx1 * C4];
        const f32x4 v10 = f4[r1 + (size_t)gx0 * C4];
        const f32x4 v11 = f4[r1 + (size_t)gx1 * C4];

        const f32x4 top = v00 * omwx + v01 * wx;
        const f32x4 bot = v10 * omwx + v11 * wx;
        const f32x4 o   = top * omwy + bot * wy;

        __builtin_nontemporal_store(o, &o4[ob + (size_t)px * C4]);
    };

    if (ps == 7) {
#pragma unroll
        for (int px = 0; px < 7; ++px) body(px);
    } else {
        for (int px = 0; px < ps; ++px) body(px);
    }
}

extern "C" void kernel_launch(void* const* d_in, const int* in_sizes, int n_in,
                              void* d_out, int out_size, void* d_ws, size_t ws_size,
                              hipStream_t stream) {
    const float* img  = (const float*)d_in[0];
    const float* rois = (const float*)d_in[1];
    float*       out  = (float*)d_out;

    const int H = 200, W = 200, C = 256;
    const int ps = 7;                            // fixed problem instance
    const int n_rows = out_size / (C * ps);      // N * ps = 14000

    // workspace layout: bins[256] | offs[256] | rowmap[n_rows]
    int* bins   = (int*)d_ws;
    int* offs   = bins + NBINS;
    int* rowmap = offs + NBINS;

    zero_bins_kernel<<<1, NBINS, 0, stream>>>(bins);
    hist_kernel<<<(n_rows + 255) / 256, 256, 0, stream>>>(rois, bins, n_rows, ps);
    scan_kernel<<<1, 64, 0, stream>>>(bins, offs);
    scatter_kernel<<<(n_rows + 255) / 256, 256, 0, stream>>>(rois, offs, rowmap, n_rows, ps);

    const int blocks = (n_rows + 3) / 4;         // 4 waves (rows) per block
    RoIPool_53575422050620_kernel<<<blocks, 256, 0, stream>>>(
        img, rois, rowmap, out, n_rows, H, W, C, ps);
}

// Round 4
// 183.768 us; speedup vs baseline: 1.0076x; 1.0076x over previous
//
#include <hip/hip_runtime.h>
#include <hip/hip_bf16.h>

// RoI bilinear pooling, XCD-locality-scheduled.
// img : (1, H=200, W=200, C=256) fp32 NHWC -> channel vectors contiguous (1 KiB)
// rois: (1, N=2000, 4) fp32 (integer-valued x,y,w,h)
// out : (1, N, ps, ps, C) fp32
//
// R3 post-mortem: (a) serial scan kernel cost ~20us (dependent global-load
// chain) -> replaced with LDS Hillis-Steele scan. (b) plain y-sort didn't
// narrow the working set because ~2000 concurrent waves span the whole sorted
// order. Fix: shard the sorted rows into 8 contiguous chunks, one per XCD
// (blocks round-robin XCDs by blockIdx%8), so each XCD's 4 MB L2 sees a
// monotone sweep over its own ~25-row image band (~800 KiB concurrent window).

typedef float f32x4 __attribute__((ext_vector_type(4)));

#define IMG_H 200
#define IMG_W 200
#define NBINS 256   // gy0 in [0,199]
#define NXCD  8

__device__ __forceinline__ int row_gy0(const float4 r, int py, int ps) {
    const int y = (int)r.y;
    const int h = (int)r.w;
    const float sy    = (float)h / (float)ps;
    const float src_y = (float)py * sy;
    const int   y0    = (int)floorf(src_y);
    return min(max(y + min(max(y0, 0), h - 1), 0), IMG_H - 1);
}

// --- pass 1: zero bins, then histogram of gy0 over all rows ---
__global__ void zero_bins_kernel(int* __restrict__ bins) {
    bins[threadIdx.x] = 0;   // 1 block x NBINS threads
}

__global__ void hist_kernel(const float* __restrict__ rois, int* __restrict__ bins,
                            int n_rows, int ps) {
    const int row = blockIdx.x * blockDim.x + threadIdx.x;
    if (row >= n_rows) return;
    const int roi = row / ps;
    const int py  = row - roi * ps;
    const float4 r = reinterpret_cast<const float4*>(rois)[roi];
    atomicAdd(&bins[row_gy0(r, py, ps)], 1);
}

// --- pass 2: parallel exclusive prefix sum over NBINS (LDS Hillis-Steele) ---
__global__ void scan_kernel(const int* __restrict__ bins, int* __restrict__ offs) {
    __shared__ int tmp[NBINS];
    const int t = threadIdx.x;
    const int v0 = bins[t];
    tmp[t] = v0;
    __syncthreads();
    for (int d = 1; d < NBINS; d <<= 1) {
        const int v = (t >= d) ? tmp[t - d] : 0;
        __syncthreads();
        tmp[t] += v;
        __syncthreads();
    }
    offs[t] = tmp[t] - v0;   // exclusive
}

// --- pass 3: scatter row ids into sorted order ---
__global__ void scatter_kernel(const float* __restrict__ rois, int* __restrict__ offs,
                               int* __restrict__ rowmap, int n_rows, int ps) {
    const int row = blockIdx.x * blockDim.x + threadIdx.x;
    if (row >= n_rows) return;
    const int roi = row / ps;
    const int py  = row - roi * ps;
    const float4 r = reinterpret_cast<const float4*>(rois)[roi];
    const int pos = atomicAdd(&offs[row_gy0(r, py, ps)], 1);
    rowmap[pos] = row;
}

// --- main kernel: one wave per output row; sorted rows sharded per-XCD so
//     each XCD's L2 sweeps one narrow horizontal image band ---
__global__ __launch_bounds__(256) void RoIPool_53575422050620_kernel(
    const float* __restrict__ feat,     // H*W*C
    const float* __restrict__ rois,     // N*4
    const int*   __restrict__ rowmap,   // sorted row ids
    float*       __restrict__ out,      // N*ps*ps*C
    int n_rows, int H, int W, int C, int ps, int per_chunk)
{
    // blocks round-robin XCDs by blockIdx % 8: give XCD x the contiguous
    // sorted chunk [x*per_chunk, (x+1)*per_chunk).
    const int xcd = blockIdx.x & (NXCD - 1);
    const int jb  = blockIdx.x >> 3;
    const int idx_in_chunk = jb * 4 + (threadIdx.x >> 6);
    if (idx_in_chunk >= per_chunk) return;
    const int slot = xcd * per_chunk + idx_in_chunk;
    if (slot >= n_rows) return;

    const int row  = rowmap[slot];
    const int lane = threadIdx.x & 63;

    const int roi = row / ps;
    const int py  = row - roi * ps;

    const float4 r = reinterpret_cast<const float4*>(rois)[roi];
    const int x = (int)r.x;   // astype(int32) == trunc; values >= 0
    const int y = (int)r.y;
    const int w = (int)r.z;
    const int h = (int)r.w;

    // y-side math, identical fp32 expression to reference
    const float sy    = (float)h / (float)ps;
    const float sx    = (float)w / (float)ps;
    const float src_y = (float)py * sy;
    const int   y0    = (int)floorf(src_y);
    const float wy    = src_y - (float)y0;
    const float omwy  = 1.0f - wy;

    const int gy0 = min(max(y + min(max(y0,     0), h - 1), 0), H - 1);
    const int gy1 = min(max(y + min(max(y0 + 1, 0), h - 1), 0), H - 1);

    const int C4 = C >> 2;   // == 64: one float4 per lane covers the channel row
    const f32x4* __restrict__ f4 = reinterpret_cast<const f32x4*>(feat);
    f32x4* __restrict__ o4 = reinterpret_cast<f32x4*>(out);

    const size_t r0 = (size_t)(gy0 * W) * C4 + lane;
    const size_t r1 = (size_t)(gy1 * W) * C4 + lane;
    const size_t ob = (size_t)row * ps * C4 + lane;

    auto body = [&](int px) {
        const float src_x = (float)px * sx;
        const int   x0    = (int)floorf(src_x);
        const float wx    = src_x - (float)x0;
        const float omwx  = 1.0f - wx;

        const int gx0 = min(max(x + min(max(x0,     0), w - 1), 0), W - 1);
        const int gx1 = min(max(x + min(max(x0 + 1, 0), w - 1), 0), W - 1);

        const f32x4 v00 = f4[r0 + (size_t)gx0 * C4];
        const f32x4 v01 = f4[r0 + (size_t)gx1 * C4];
        const f32x4 v10 = f4[r1 + (size_t)gx0 * C4];
        const f32x4 v11 = f4[r1 + (size_t)gx1 * C4];

        const f32x4 top = v00 * omwx + v01 * wx;
        const f32x4 bot = v10 * omwx + v11 * wx;
        const f32x4 o   = top * omwy + bot * wy;

        __builtin_nontemporal_store(o, &o4[ob + (size_t)px * C4]);
    };

    if (ps == 7) {
#pragma unroll
        for (int px = 0; px < 7; ++px) body(px);
    } else {
        for (int px = 0; px < ps; ++px) body(px);
    }
}

extern "C" void kernel_launch(void* const* d_in, const int* in_sizes, int n_in,
                              void* d_out, int out_size, void* d_ws, size_t ws_size,
                              hipStream_t stream) {
    const float* img  = (const float*)d_in[0];
    const float* rois = (const float*)d_in[1];
    float*       out  = (float*)d_out;

    const int H = 200, W = 200, C = 256;
    const int ps = 7;                            // fixed problem instance
    const int n_rows = out_size / (C * ps);      // N * ps = 14000

    // workspace layout: bins[256] | offs[256] | rowmap[n_rows]
    int* bins   = (int*)d_ws;
    int* offs   = bins + NBINS;
    int* rowmap = offs + NBINS;

    zero_bins_kernel<<<1, NBINS, 0, stream>>>(bins);
    hist_kernel<<<(n_rows + 255) / 256, 256, 0, stream>>>(rois, bins, n_rows, ps);
    scan_kernel<<<1, NBINS, 0, stream>>>(bins, offs);
    scatter_kernel<<<(n_rows + 255) / 256, 256, 0, stream>>>(rois, offs, rowmap, n_rows, ps);

    const int per_chunk = (n_rows + NXCD - 1) / NXCD;        // 1750
    const int blocks_per_chunk = (per_chunk + 3) / 4;        // 438
    const int blocks = blocks_per_chunk * NXCD;              // 3504

    RoIPool_53575422050620_kernel<<<blocks, 256, 0, stream>>>(
        img, rois, rowmap, out, n_rows, H, W, C, ps, per_chunk);
}

// Round 5
// 180.203 us; speedup vs baseline: 1.0276x; 1.0198x over previous
//
#include <hip/hip_runtime.h>
#include <hip/hip_bf16.h>

// RoI bilinear pooling, locality-scheduled (plain y-sort, fused sort kernel).
// img : (1, H=200, W=200, C=256) fp32 NHWC -> channel vectors contiguous (1 KiB)
// rois: (1, N=2000, 4) fp32 (integer-valued x,y,w,h)
// out : (1, N, ps, ps, C) fp32
//
// R4 post-mortem: XCD %8 sharding regressed the main kernel (either blockIdx%8
// is not the XCD map under this dispatch, or disjoint per-XCD bands defeat
// L3-level sharing). Reconstruction from totals says R3's PLAIN sorted order
// had the main kernel at ~41us but its serial scan burned ~40us. This round:
// plain sorted order + ONE fused sort kernel (single workgroup, LDS histogram
// + LDS scan + scatter) -> 2 dispatches total.

typedef float f32x4 __attribute__((ext_vector_type(4)));

#define IMG_H 200
#define IMG_W 200
#define NBINS 256   // gy0 in [0,199]

__device__ __forceinline__ int row_gy0(const float4 r, int py, int ps) {
    const int y = (int)r.y;
    const int h = (int)r.w;
    const float sy    = (float)h / (float)ps;
    const float src_y = (float)py * sy;
    const int   y0    = (int)floorf(src_y);
    return min(max(y + min(max(y0, 0), h - 1), 0), IMG_H - 1);
}

// --- fused counting sort: one workgroup, LDS-only histogram+scan ---
__global__ __launch_bounds__(1024) void sort_rows_kernel(
    const float* __restrict__ rois, int* __restrict__ rowmap, int n_rows, int ps)
{
    __shared__ int sbins[NBINS];
    __shared__ int soffs[NBINS];
    const int t = threadIdx.x;

    if (t < NBINS) sbins[t] = 0;
    __syncthreads();

    // histogram (LDS atomics; rois 32 KB -> L2-hot after first touch)
    for (int row = t; row < n_rows; row += 1024) {
        const int roi = row / ps;
        const int py  = row - roi * ps;
        const float4 r = reinterpret_cast<const float4*>(rois)[roi];
        atomicAdd(&sbins[row_gy0(r, py, ps)], 1);
    }
    __syncthreads();

    // exclusive scan over NBINS (Hillis-Steele, threads < NBINS participate)
    if (t < NBINS) soffs[t] = sbins[t];
    __syncthreads();
    for (int d = 1; d < NBINS; d <<= 1) {
        int v = 0;
        if (t < NBINS && t >= d) v = soffs[t - d];
        __syncthreads();
        if (t < NBINS) soffs[t] += v;
        __syncthreads();
    }
    if (t < NBINS) soffs[t] -= sbins[t];   // inclusive -> exclusive
    __syncthreads();

    // scatter
    for (int row = t; row < n_rows; row += 1024) {
        const int roi = row / ps;
        const int py  = row - roi * ps;
        const float4 r = reinterpret_cast<const float4*>(rois)[roi];
        const int pos = atomicAdd(&soffs[row_gy0(r, py, ps)], 1);
        rowmap[pos] = row;
    }
}

// --- main kernel: one wave per output row, rows visited in sorted-y order ---
__global__ __launch_bounds__(256) void RoIPool_53575422050620_kernel(
    const float* __restrict__ feat,     // H*W*C
    const float* __restrict__ rois,     // N*4
    const int*   __restrict__ rowmap,   // sorted row ids
    float*       __restrict__ out,      // N*ps*ps*C
    int n_rows, int H, int W, int C, int ps)
{
    const int slot = blockIdx.x * 4 + (threadIdx.x >> 6);
    if (slot >= n_rows) return;
    const int row  = rowmap[slot];
    const int lane = threadIdx.x & 63;

    const int roi = row / ps;
    const int py  = row - roi * ps;

    const float4 r = reinterpret_cast<const float4*>(rois)[roi];
    const int x = (int)r.x;   // astype(int32) == trunc; values >= 0
    const int y = (int)r.y;
    const int w = (int)r.z;
    const int h = (int)r.w;

    // y-side math, identical fp32 expression to reference
    const float sy    = (float)h / (float)ps;
    const float sx    = (float)w / (float)ps;
    const float src_y = (float)py * sy;
    const int   y0    = (int)floorf(src_y);
    const float wy    = src_y - (float)y0;
    const float omwy  = 1.0f - wy;

    const int gy0 = min(max(y + min(max(y0,     0), h - 1), 0), H - 1);
    const int gy1 = min(max(y + min(max(y0 + 1, 0), h - 1), 0), H - 1);

    const int C4 = C >> 2;   // == 64: one float4 per lane covers the channel row
    const f32x4* __restrict__ f4 = reinterpret_cast<const f32x4*>(feat);
    f32x4* __restrict__ o4 = reinterpret_cast<f32x4*>(out);

    const size_t r0 = (size_t)(gy0 * W) * C4 + lane;
    const size_t r1 = (size_t)(gy1 * W) * C4 + lane;
    const size_t ob = (size_t)row * ps * C4 + lane;

    auto body = [&](int px) {
        const float src_x = (float)px * sx;
        const int   x0    = (int)floorf(src_x);
        const float wx    = src_x - (float)x0;
        const float omwx  = 1.0f - wx;

        const int gx0 = min(max(x + min(max(x0,     0), w - 1), 0), W - 1);
        const int gx1 = min(max(x + min(max(x0 + 1, 0), w - 1), 0), W - 1);

        const f32x4 v00 = f4[r0 + (size_t)gx0 * C4];
        const f32x4 v01 = f4[r0 + (size_t)gx1 * C4];
        const f32x4 v10 = f4[r1 + (size_t)gx0 * C4];
        const f32x4 v11 = f4[r1 + (size_t)gx1 * C4];

        const f32x4 top = v00 * omwx + v01 * wx;
        const f32x4 bot = v10 * omwx + v11 * wx;
        const f32x4 o   = top * omwy + bot * wy;

        __builtin_nontemporal_store(o, &o4[ob + (size_t)px * C4]);
    };

    if (ps == 7) {
#pragma unroll
        for (int px = 0; px < 7; ++px) body(px);
    } else {
        for (int px = 0; px < ps; ++px) body(px);
    }
}

extern "C" void kernel_launch(void* const* d_in, const int* in_sizes, int n_in,
                              void* d_out, int out_size, void* d_ws, size_t ws_size,
                              hipStream_t stream) {
    const float* img  = (const float*)d_in[0];
    const float* rois = (const float*)d_in[1];
    float*       out  = (float*)d_out;

    const int H = 200, W = 200, C = 256;
    const int ps = 7;                            // fixed problem instance
    const int n_rows = out_size / (C * ps);      // N * ps = 14000

    int* rowmap = (int*)d_ws;                    // 14000 ints

    sort_rows_kernel<<<1, 1024, 0, stream>>>(rois, rowmap, n_rows, ps);

    const int blocks = (n_rows + 3) / 4;         // 4 waves (rows) per block
    RoIPool_53575422050620_kernel<<<blocks, 256, 0, stream>>>(
        img, rois, rowmap, out, n_rows, H, W, C, ps);
}

// Round 6
// 169.407 us; speedup vs baseline: 1.0930x; 1.0637x over previous
//
#include <hip/hip_runtime.h>
#include <hip/hip_bf16.h>

// RoI bilinear pooling — MLP-maximized, single dispatch.
// img : (1, H=200, W=200, C=256) fp32 NHWC -> channel vectors contiguous (1 KiB)
// rois: (1, N=2000, 4) fp32 (integer-valued x,y,w,h)
// out : (1, N, ps, ps, C) fp32
//
// R5 post-mortem: sorting/locality scheduling never moved the main kernel
// (~65 us with or without); dropped. Root cause of the 4 TB/s plateau was
// VGPR_Count=32 -> compiler serialized the px loop into 7 dependent
// load->waitcnt(0)->store rounds (latency-bound, ~150 issue cycles per 400
// cycle wait). Fix: full-row prefetch — all 28 float4 taps issued before any
// compute — under __launch_bounds__(256,2) (VGPR cap 256). In-flight
// loads/CU rises ~80 -> ~224.

typedef float f32x4 __attribute__((ext_vector_type(4)));

__global__ __launch_bounds__(256, 2) void RoIPool_53575422050620_kernel(
    const float* __restrict__ feat,   // H*W*C
    const float* __restrict__ rois,   // N*4
    const int*   __restrict__ psp,    // pool_size scalar
    float*       __restrict__ out,    // N*ps*ps*C
    int n_rows, int H, int W, int C)  // n_rows = N*ps
{
    const int ps  = psp[0];
    const int row = blockIdx.x * 4 + (threadIdx.x >> 6);   // (roi*ps + py)
    if (row >= n_rows) return;
    const int lane = threadIdx.x & 63;

    const int roi = row / ps;
    const int py  = row - roi * ps;

    const float4 r = reinterpret_cast<const float4*>(rois)[roi];
    const int x = (int)r.x;   // astype(int32) == trunc; values >= 0
    const int y = (int)r.y;
    const int w = (int)r.z;
    const int h = (int)r.w;

    // y-side math, identical fp32 expression to reference
    const float sy    = (float)h / (float)ps;
    const float sx    = (float)w / (float)ps;
    const float src_y = (float)py * sy;
    const int   y0    = (int)floorf(src_y);
    const float wy    = src_y - (float)y0;
    const float omwy  = 1.0f - wy;

    const int gy0 = min(max(y + min(max(y0,     0), h - 1), 0), H - 1);
    const int gy1 = min(max(y + min(max(y0 + 1, 0), h - 1), 0), H - 1);

    const int C4 = C >> 2;   // == 64: one float4 per lane covers the channel row
    const f32x4* __restrict__ f4 = reinterpret_cast<const f32x4*>(feat);
    f32x4* __restrict__ o4 = reinterpret_cast<f32x4*>(out);

    const size_t r0 = (size_t)(gy0 * W) * C4 + lane;
    const size_t r1 = (size_t)(gy1 * W) * C4 + lane;
    const size_t ob = (size_t)row * ps * C4 + lane;

    if (ps == 7) {
        // ---- phase 1: all x-side indices/weights (VALU only) ----
        int   gx0a[7], gx1a[7];
        float wxa[7];
#pragma unroll
        for (int px = 0; px < 7; ++px) {
            const float src_x = (float)px * sx;
            const int   x0    = (int)floorf(src_x);
            wxa[px]  = src_x - (float)x0;
            gx0a[px] = min(max(x + min(max(x0,     0), w - 1), 0), W - 1);
            gx1a[px] = min(max(x + min(max(x0 + 1, 0), w - 1), 0), W - 1);
        }

        // ---- phase 2: issue ALL 28 tap loads before any use ----
        f32x4 v00[7], v01[7], v10[7], v11[7];
#pragma unroll
        for (int px = 0; px < 7; ++px) {
            v00[px] = f4[r0 + (size_t)gx0a[px] * C4];
            v01[px] = f4[r0 + (size_t)gx1a[px] * C4];
            v10[px] = f4[r1 + (size_t)gx0a[px] * C4];
            v11[px] = f4[r1 + (size_t)gx1a[px] * C4];
        }

        // ---- phase 3: compute + store (identical fp32 expression to ref) ----
#pragma unroll
        for (int px = 0; px < 7; ++px) {
            const float wx = wxa[px], omwx = 1.0f - wx;
            const f32x4 top = v00[px] * omwx + v01[px] * wx;
            const f32x4 bot = v10[px] * omwx + v11[px] * wx;
            const f32x4 o   = top * omwy + bot * wy;
            __builtin_nontemporal_store(o, &o4[ob + (size_t)px * C4]);
        }
    } else {
        for (int px = 0; px < ps; ++px) {
            const float src_x = (float)px * sx;
            const int   x0    = (int)floorf(src_x);
            const float wx    = src_x - (float)x0;
            const float omwx  = 1.0f - wx;
            const int gx0 = min(max(x + min(max(x0,     0), w - 1), 0), W - 1);
            const int gx1 = min(max(x + min(max(x0 + 1, 0), w - 1), 0), W - 1);
            const f32x4 v00 = f4[r0 + (size_t)gx0 * C4];
            const f32x4 v01 = f4[r0 + (size_t)gx1 * C4];
            const f32x4 v10 = f4[r1 + (size_t)gx0 * C4];
            const f32x4 v11 = f4[r1 + (size_t)gx1 * C4];
            const f32x4 top = v00 * omwx + v01 * wx;
            const f32x4 bot = v10 * omwx + v11 * wx;
            const f32x4 o   = top * omwy + bot * wy;
            __builtin_nontemporal_store(o, &o4[ob + (size_t)px * C4]);
        }
    }
}

extern "C" void kernel_launch(void* const* d_in, const int* in_sizes, int n_in,
                              void* d_out, int out_size, void* d_ws, size_t ws_size,
                              hipStream_t stream) {
    const float* img  = (const float*)d_in[0];
    const float* rois = (const float*)d_in[1];
    const int*   psp  = (const int*)d_in[2];
    float*       out  = (float*)d_out;

    const int H = 200, W = 200, C = 256;
    const int ps = 7;                            // fixed problem instance
    const int n_rows = out_size / (C * ps);      // N * ps = 14000
    const int blocks = (n_rows + 3) / 4;         // 4 waves (rows) per block

    RoIPool_53575422050620_kernel<<<blocks, 256, 0, stream>>>(
        img, rois, psp, out, n_rows, H, W, C);
}